// Round 10
// baseline (491.467 us; speedup 1.0000x reference)
//
#include <hip/hip_runtime.h>
#include <hip/hip_bf16.h>
#include <stdint.h>

typedef unsigned short u16;

#define Adim 512
#define Ndim 128
#define Fdim 256
#define BA 2048

#define HS 264      // bf16 row stride: 528 B, 16B-aligned, 4-dword bank rotation per row
#define XS 264

#define GRID 512
#define ITEMS 8     // 4096 half-pair items / 512 blocks

typedef __attribute__((ext_vector_type(8))) __bf16 bf16x8;
typedef __attribute__((ext_vector_type(4))) float f32x4;

__device__ __forceinline__ float bf2f(u16 u){
  uint32_t v = ((uint32_t)u) << 16;
  return __builtin_bit_cast(float, v);
}
// hardware packed f32->bf16 RNE: 2 converts in 1 instr (v_cvt_pk_bf16_f32)
__device__ __forceinline__ uint32_t cvtpk(float lo, float hi){
  uint32_t r;
  asm("v_cvt_pk_bf16_f32 %0, %1, %2" : "=v"(r) : "v"(lo), "v"(hi));
  return r;
}
__device__ __forceinline__ u16 f2bf(float f){ return (u16)cvtpk(f, f); }
// softplus(v) - log(2), stable both tails
__device__ __forceinline__ float ssp_f(float v){
  float m = fmaxf(v, 0.f);
  float e = __expf(-fabsf(v));
  return m + __logf(1.f + e) - 0.69314718f;
}

// ---------------- prep: transpose fp32 256x256 -> bf16 [n][k], x3 ----------------
__global__ __launch_bounds__(256) void prep_kernel(
    const float* __restrict__ s0, u16* __restrict__ d0,
    const float* __restrict__ s1, u16* __restrict__ d1,
    const float* __restrict__ s2, u16* __restrict__ d2)
{
  __shared__ float tile[32][33];
  const float* src = (blockIdx.y == 0) ? s0 : (blockIdx.y == 1 ? s1 : s2);
  u16* dst = (blockIdx.y == 0) ? d0 : (blockIdx.y == 1 ? d1 : d2);
  int bx = (blockIdx.x & 7) * 32, by = (int)(blockIdx.x >> 3) * 32;
  int tx = threadIdx.x & 31, ty = threadIdx.x >> 5;
  #pragma unroll
  for (int r = 0; r < 4; r++)
    tile[ty + r*8][tx] = src[(size_t)(by + ty + r*8)*Fdim + bx + tx];
  __syncthreads();
  #pragma unroll
  for (int r = 0; r < 4; r++)
    dst[(size_t)(bx + ty + r*8)*Fdim + by + tx] = f2bf(tile[tx][ty + r*8]);
}

// ---------------- facts = x @ in2f_w + b  (MFMA, bf16 out) ----------------
__global__ __launch_bounds__(256, 2) void facts_kernel(
    const float* __restrict__ x, const u16* __restrict__ wT,
    const float* __restrict__ bias, u16* __restrict__ facts)
{
  __shared__ __align__(16) u16 Xs[64*HS];
  const int tid = threadIdx.x;
  const int row0 = blockIdx.x * 64;

  #pragma unroll
  for (int i = 0; i < 16; i++){
    int id = i*256 + tid;
    int r = id >> 6, c4 = id & 63;
    float4 v = *(const float4*)(x + (size_t)(row0 + r)*Fdim + c4*4);
    uint2 q;
    q.x = cvtpk(v.x, v.y);
    q.y = cvtpk(v.z, v.w);
    *(uint2*)(Xs + r*HS + c4*4) = q;
  }
  __syncthreads();

  const int lane = tid & 63, wid = tid >> 6;
  const int wcol = wid * 64;
  const int l16 = lane & 15, quad = lane >> 4;

  f32x4 acc[4][4];
  #pragma unroll
  for (int mt = 0; mt < 4; mt++)
    #pragma unroll
    for (int ct = 0; ct < 4; ct++)
      acc[mt][ct] = (f32x4){0.f,0.f,0.f,0.f};

  const u16* wbase = wT + (size_t)(wcol + l16)*Fdim + quad*8;
  bf16x8 bb[2][4];
  #pragma unroll
  for (int ct = 0; ct < 4; ct++) bb[0][ct] = *(const bf16x8*)(wbase + ct*16*Fdim);

  for (int kk = 0; kk < 8; kk++){
    if (kk < 7){
      #pragma unroll
      for (int ct = 0; ct < 4; ct++)
        bb[(kk+1)&1][ct] = *(const bf16x8*)(wbase + ct*16*Fdim + (kk+1)*32);
    }
    bf16x8 af[4];
    #pragma unroll
    for (int mt = 0; mt < 4; mt++)
      af[mt] = *(const bf16x8*)(Xs + (mt*16 + l16)*HS + kk*32 + quad*8);
    #pragma unroll
    for (int mt = 0; mt < 4; mt++)
      #pragma unroll
      for (int ct = 0; ct < 4; ct++)
        acc[mt][ct] = __builtin_amdgcn_mfma_f32_16x16x32_bf16(af[mt], bb[kk&1][ct], acc[mt][ct], 0, 0, 0);
  }

  #pragma unroll
  for (int ct = 0; ct < 4; ct++){
    int f = wcol + ct*16 + l16;
    float bv = bias[f];
    #pragma unroll
    for (int mt = 0; mt < 4; mt++)
      #pragma unroll
      for (int i = 0; i < 4; i++){
        int m = mt*16 + quad*4 + i;
        facts[(size_t)(row0 + m)*Fdim + f] = f2bf(acc[mt][ct][i] + bv);
      }
  }
}

// ---- fused, persistent, software-pipelined across items ----
// R9 lesson: barrier count wasn't it either. With 1 block/CU, all 8 waves march
// phase-lockstep: MFMA phases starve VALU and vice versa. This round pipelines
// items so each barrier-delimited region mixes pipes in ONE instruction stream:
//   P1: epi(l-1) [VALU+NT stores] || gather(l+1) [VMEM] || gemm1(l) [MFMA]
//   a  P2: ew(l) + H-gen(l+1) [VALU]   (Hs write post-a, read post-b: race-free)
//   b  P3: gemm2(l) [MFMA]
// Hazards: Hs W@P2(l)/R@P1(l+1) cross b; Ys W@P2(l)/R-prev@P3(l-1) cross a;
// XJ + nb/r double-buffered. accZ lives across the loop edge (+32 regs, budget 256 ok).
__global__ __launch_bounds__(512, 2) void fused_kernel(
    const float* __restrict__ r_ij, const u16* __restrict__ facts,
    const u16* __restrict__ fw2T, const u16* __restrict__ f2outT,
    const float* __restrict__ fw1, const float* __restrict__ fb1,
    const float* __restrict__ fb2, const float* __restrict__ f2out_b,
    const int* __restrict__ neighbors, float* __restrict__ out)
{
  __shared__ __align__(16) u16 Hs[64*HS];      // 33792 B (H only)
  __shared__ __align__(16) u16 XJ[2][64*XS];   // 2 x 33792 B
  __shared__ __align__(16) u16 Ys[64*HS];      // 33792 B (Y only)
  __shared__ int   nb_s[2][64];
  __shared__ float r_s[2][64];

  const int tid  = threadIdx.x;
  const int lane = tid & 63, wid = tid >> 6;
  const int l16  = lane & 15, quad = lane >> 4;
  const int wcol = wid * 32;                 // 8 waves x 32-col n-slices
  const int g    = tid & 31;                 // gather/H-gen column group (invariant)
  const int rsub = tid >> 5;                 // row sub-index (invariant)

  // ---- per-thread kernel-lifetime register caches ----
  float fw1v[8], fb1v[8];
  *(float4*)(fw1v)   = *(const float4*)(fw1 + g*8);
  *(float4*)(fw1v+4) = *(const float4*)(fw1 + g*8 + 4);
  *(float4*)(fb1v)   = *(const float4*)(fb1 + g*8);
  *(float4*)(fb1v+4) = *(const float4*)(fb1 + g*8 + 4);
  float fb2v[2], obv[2];
  #pragma unroll
  for (int ct = 0; ct < 2; ct++){
    int f = wcol + ct*16 + l16;
    fb2v[ct] = fb2[f];
    obv[ct]  = f2out_b[f];
  }

  const u16* w1base = fw2T   + (size_t)(wcol + l16)*Fdim + quad*8;
  const u16* w2base = f2outT + (size_t)(wcol + l16)*Fdim + quad*8;

  f32x4 accW[4][2], accZ[4][2];
  #pragma unroll
  for (int mt = 0; mt < 4; mt++)
    #pragma unroll
    for (int ct = 0; ct < 2; ct++){
      accW[mt][ct] = (f32x4){0.f,0.f,0.f,0.f};
      accZ[mt][ct] = (f32x4){0.f,0.f,0.f,0.f};
    }

  bf16x8 bw[4][2];   // 32 VGPRs: half-K weight buffer, reloaded mid-GEMM

  // ---- prologue: nb/r(0) -> buf0; stage(0); nb/r(1) -> buf1 ----
  {
    const int it0 = blockIdx.x;
    const int p0 = it0 >> 1, h0 = it0 & 1;
    if (tid < 64){
      nb_s[0][tid] = neighbors[(size_t)p0*Ndim + h0*64 + tid];
      r_s[0][tid]  = r_ij[(size_t)p0*Ndim + h0*64 + tid];
    }
  }
  __syncthreads();
  {
    const int it0 = blockIdx.x;
    const int p0 = it0 >> 1;
    const int bb0 = (p0 >> 9) << 9;
    float4 g0[4];
    #pragma unroll
    for (int i = 0; i < 4; i++){
      int row = i*16 + rsub;
      g0[i] = *(const float4*)(facts + ((size_t)(bb0 + nb_s[0][row]))*Fdim + g*8);
    }
    #pragma unroll
    for (int i = 0; i < 4; i++){
      int row = i*16 + rsub;
      float rv = r_s[0][row];
      float h[8];
      #pragma unroll
      for (int j = 0; j < 8; j++)
        h[j] = ssp_f(fmaf(rv, fw1v[j], fb1v[j]));
      uint4 pw;
      pw.x = cvtpk(h[0], h[1]);
      pw.y = cvtpk(h[2], h[3]);
      pw.z = cvtpk(h[4], h[5]);
      pw.w = cvtpk(h[6], h[7]);
      *(uint4*)(Hs + row*HS + g*8) = pw;
    }
    #pragma unroll
    for (int i = 0; i < 4; i++){
      int row = i*16 + rsub;
      *(float4*)(XJ[0] + row*XS + g*8) = g0[i];
    }
    if (tid < 64){
      const int it1 = GRID + blockIdx.x;
      const int p1 = it1 >> 1, h1 = it1 & 1;
      nb_s[1][tid] = neighbors[(size_t)p1*Ndim + h1*64 + tid];
      r_s[1][tid]  = r_ij[(size_t)p1*Ndim + h1*64 + tid];
    }
  }
  __syncthreads();

  for (int l = 0; l < ITEMS; l++){
    const int item = l*GRID + blockIdx.x;
    const int pair = item >> 1;
    const int half = item & 1;
    const int pa = l & 1, pb = (l+1) & 1;

    // ===== P1: epi(l-1) || gather(l+1) || gemm1(l) =====
    #pragma unroll
    for (int kk = 0; kk < 4; kk++)
      #pragma unroll
      for (int ct = 0; ct < 2; ct++)
        bw[kk][ct] = *(const bf16x8*)(w1base + ct*16*Fdim + kk*32);

    float4 gx[4];
    if (l + 1 < ITEMS){
      const int it1 = (l+1)*GRID + blockIdx.x;
      const int p1 = it1 >> 1;
      const int bb1 = (p1 >> 9) << 9;
      #pragma unroll
      for (int i = 0; i < 4; i++){
        int row = i*16 + rsub;
        gx[i] = *(const float4*)(facts + ((size_t)(bb1 + nb_s[pb][row]))*Fdim + g*8);
      }
    }

    int nb_nxt = 0; float r_nxt = 0.f;
    if (l + 2 < ITEMS && tid < 64){
      const int it2 = (l+2)*GRID + blockIdx.x;
      const int p2i = it2 >> 1, h2 = it2 & 1;
      nb_nxt = neighbors[(size_t)p2i*Ndim + h2*64 + tid];
      r_nxt  = r_ij[(size_t)p2i*Ndim + h2*64 + tid];
    }

    float xif[2];
    #pragma unroll
    for (int ct = 0; ct < 2; ct++)
      xif[ct] = bf2f(facts[(size_t)pair*Fdim + wcol + ct*16 + l16]);

    if (l > 0){
      const int pit = item - GRID;
      const int pp = pit >> 1, ph = pit & 1;
      size_t ob = ((size_t)pp * Ndim + ph*64) * Fdim;
      #pragma unroll
      for (int ct = 0; ct < 2; ct++){
        int f = wcol + ct*16 + l16;
        #pragma unroll
        for (int mt = 0; mt < 4; mt++){
          #pragma unroll
          for (int i = 0; i < 4; i++){
            int m = mt*16 + quad*4 + i;
            __builtin_nontemporal_store(ssp_f(accZ[mt][ct][i] + obv[ct]),
                                        out + ob + (size_t)m*Fdim + f);
            accZ[mt][ct][i] = 0.f;
          }
        }
      }
    }

    // gemm1 half-1
    #pragma unroll
    for (int kk = 0; kk < 4; kk++){
      bf16x8 af[4];
      #pragma unroll
      for (int mt = 0; mt < 4; mt++)
        af[mt] = *(const bf16x8*)(Hs + (mt*16 + l16)*HS + kk*32 + quad*8);
      #pragma unroll
      for (int mt = 0; mt < 4; mt++)
        #pragma unroll
        for (int ct = 0; ct < 2; ct++)
          accW[mt][ct] = __builtin_amdgcn_mfma_f32_16x16x32_bf16(af[mt], bw[kk][ct], accW[mt][ct], 0, 0, 0);
    }
    // spill gathered xj (latency hidden under gemm1-h1 MFMA + epi VALU)
    if (l + 1 < ITEMS){
      #pragma unroll
      for (int i = 0; i < 4; i++){
        int row = i*16 + rsub;
        *(float4*)(XJ[pb] + row*XS + g*8) = gx[i];
      }
    }
    __builtin_amdgcn_sched_barrier(0);   // keep w1-h2 loads below
    #pragma unroll
    for (int kk = 0; kk < 4; kk++)
      #pragma unroll
      for (int ct = 0; ct < 2; ct++)
        bw[kk][ct] = *(const bf16x8*)(w1base + ct*16*Fdim + (kk+4)*32);
    #pragma unroll
    for (int kk = 0; kk < 4; kk++){
      bf16x8 af[4];
      #pragma unroll
      for (int mt = 0; mt < 4; mt++)
        af[mt] = *(const bf16x8*)(Hs + (mt*16 + l16)*HS + (kk+4)*32 + quad*8);
      #pragma unroll
      for (int mt = 0; mt < 4; mt++)
        #pragma unroll
        for (int ct = 0; ct < 2; ct++)
          accW[mt][ct] = __builtin_amdgcn_mfma_f32_16x16x32_bf16(af[mt], bw[kk][ct], accW[mt][ct], 0, 0, 0);
    }
    __syncthreads();   // alpha: Hs reads(gemm1) + XJ[pb] writes + Ys reads(prev gemm2) ordered

    // ===== P2: ew(l) + H-gen(l+1) =====
    if (l + 2 < ITEMS && tid < 64){
      nb_s[pa][tid] = nb_nxt;
      r_s[pa][tid]  = r_nxt;
    }
    #pragma unroll
    for (int kk = 0; kk < 4; kk++)
      #pragma unroll
      for (int ct = 0; ct < 2; ct++)
        bw[kk][ct] = *(const bf16x8*)(w2base + ct*16*Fdim + kk*32);

    #pragma unroll
    for (int ct = 0; ct < 2; ct++){
      int f = wcol + ct*16 + l16;
      #pragma unroll
      for (int mt = 0; mt < 4; mt++){
        #pragma unroll
        for (int i = 0; i < 4; i++){
          int m = mt*16 + quad*4 + i;       // C/D layout: col=lane&15, row=quad*4+i
          float wv = accW[mt][ct][i] + fb2v[ct];
          float y  = xif[ct] * wv * bf2f(XJ[pa][m*XS + f]);
          Ys[m*HS + f] = f2bf(y);
          accW[mt][ct][i] = 0.f;
        }
      }
    }

    if (l + 1 < ITEMS){
      #pragma unroll
      for (int i = 0; i < 4; i++){
        int row = i*16 + rsub;
        float rv = r_s[pb][row];
        float h[8];
        #pragma unroll
        for (int j = 0; j < 8; j++)
          h[j] = ssp_f(fmaf(rv, fw1v[j], fb1v[j]));
        uint4 pw;
        pw.x = cvtpk(h[0], h[1]);
        pw.y = cvtpk(h[2], h[3]);
        pw.z = cvtpk(h[4], h[5]);
        pw.w = cvtpk(h[6], h[7]);
        *(uint4*)(Hs + row*HS + g*8) = pw;
      }
    }
    __syncthreads();   // beta: Ys + Hs(l+1) + nb/r commit visible

    // ===== P3: gemm2(l) =====
    #pragma unroll
    for (int kk = 0; kk < 4; kk++){
      bf16x8 af[4];
      #pragma unroll
      for (int mt = 0; mt < 4; mt++)
        af[mt] = *(const bf16x8*)(Ys + (mt*16 + l16)*HS + kk*32 + quad*8);
      #pragma unroll
      for (int mt = 0; mt < 4; mt++)
        #pragma unroll
        for (int ct = 0; ct < 2; ct++)
          accZ[mt][ct] = __builtin_amdgcn_mfma_f32_16x16x32_bf16(af[mt], bw[kk][ct], accZ[mt][ct], 0, 0, 0);
    }
    __builtin_amdgcn_sched_barrier(0);   // keep w2-h2 loads below
    #pragma unroll
    for (int kk = 0; kk < 4; kk++)
      #pragma unroll
      for (int ct = 0; ct < 2; ct++)
        bw[kk][ct] = *(const bf16x8*)(w2base + ct*16*Fdim + (kk+4)*32);
    #pragma unroll
    for (int kk = 0; kk < 4; kk++){
      bf16x8 af[4];
      #pragma unroll
      for (int mt = 0; mt < 4; mt++)
        af[mt] = *(const bf16x8*)(Ys + (mt*16 + l16)*HS + (kk+4)*32 + quad*8);
      #pragma unroll
      for (int mt = 0; mt < 4; mt++)
        #pragma unroll
        for (int ct = 0; ct < 2; ct++)
          accZ[mt][ct] = __builtin_amdgcn_mfma_f32_16x16x32_bf16(af[mt], bw[kk][ct], accZ[mt][ct], 0, 0, 0);
    }
    // no barrier at loop end: epi(l) runs in next P1 (register-local);
    // gemm1(l+1) reads Hs written pre-beta.
  }

  // ---- final epilogue: item ITEMS-1 ----
  {
    const int item = (ITEMS-1)*GRID + blockIdx.x;
    const int pp = item >> 1, ph = item & 1;
    size_t ob = ((size_t)pp * Ndim + ph*64) * Fdim;
    #pragma unroll
    for (int ct = 0; ct < 2; ct++){
      int f = wcol + ct*16 + l16;
      #pragma unroll
      for (int mt = 0; mt < 4; mt++){
        #pragma unroll
        for (int i = 0; i < 4; i++){
          int m = mt*16 + quad*4 + i;
          __builtin_nontemporal_store(ssp_f(accZ[mt][ct][i] + obv[ct]),
                                      out + ob + (size_t)m*Fdim + f);
        }
      }
    }
  }
}

extern "C" void kernel_launch(void* const* d_in, const int* in_sizes, int n_in,
                              void* d_out, int out_size, void* d_ws, size_t ws_size,
                              hipStream_t stream)
{
  const float* x        = (const float*)d_in[0];
  const float* r_ij     = (const float*)d_in[1];
  // d_in[2] pairwise_mask: unused by the reference (all-ones)
  const float* in2f_w   = (const float*)d_in[3];
  const float* in2f_b   = (const float*)d_in[4];
  const float* f2out_w  = (const float*)d_in[5];
  const float* f2out_b  = (const float*)d_in[6];
  const float* fw1      = (const float*)d_in[7];
  const float* fb1      = (const float*)d_in[8];
  const float* fw2      = (const float*)d_in[9];
  const float* fb2      = (const float*)d_in[10];
  const int*   neighbors= (const int*)d_in[11];
  float* out = (float*)d_out;

  u16* facts  = (u16*)d_ws;                                        // 1 MiB
  u16* in2fT  = (u16*)((char*)d_ws + (1u<<20));                    // 128 KiB
  u16* fw2T   = (u16*)((char*)d_ws + (1u<<20) + 1*(1u<<17));       // 128 KiB
  u16* f2outT = (u16*)((char*)d_ws + (1u<<20) + 2*(1u<<17));       // 128 KiB

  prep_kernel<<<dim3(64, 3), 256, 0, stream>>>(in2f_w, in2fT, fw2, fw2T, f2out_w, f2outT);
  facts_kernel<<<32, 256, 0, stream>>>(x, in2fT, in2f_b, facts);
  fused_kernel<<<GRID, 512, 0, stream>>>(r_ij, facts, fw2T, f2outT,
                                         fw1, fb1, fb2, f2out_b, neighbors, out);
}